// Round 4
// baseline (299.155 us; speedup 1.0000x reference)
//
#include <hip/hip_runtime.h>
#include <hip/hip_bf16.h>
#include <stdint.h>

#define ALPHA_ 0.2f
#define EPS_   1e-6f

typedef __attribute__((ext_vector_type(8))) short  short8;
typedef __attribute__((ext_vector_type(4))) float  float4v;

union U8 { short8 s8; unsigned int u[4]; uint4 v4; };

static __device__ __forceinline__ unsigned short f2bf(float x) {
    union { float f; unsigned int u; } c; c.f = x;
    return (unsigned short)((c.u + 0x7fffu + ((c.u >> 16) & 1u)) >> 16);
}

// async global->LDS, 16B per lane: LDS dest = uniform base + lane*16
#define GLOAD_LDS16(g, l)                                                      \
    __builtin_amdgcn_global_load_lds(                                          \
        (const __attribute__((address_space(1))) unsigned int*)(g),            \
        (__attribute__((address_space(3))) unsigned int*)(l), 16, 0, 0)

// ---------------- K0: WT in MFMA-B-fragment order ---------------------------
// frag (fb in 0..15, kc in 0..7), lane l: 8 halves = W[kc*32+quad*8+i][fb*16+m]
// stored at WTs[((fb*8+kc)*64 + l)*8]  -> k_wh reads lane-contiguous 1KB/instr
__global__ __launch_bounds__(256) void k_wt(const float* __restrict__ W,
                                            unsigned short* __restrict__ WTs) {
    const int g  = blockIdx.x * 256 + threadIdx.x;   // 8192 threads
    const int fb = g >> 9, kc = (g >> 6) & 7, l = g & 63;
    const int m = l & 15, quad = l >> 4;
    const int f = fb * 16 + m, d0 = kc * 32 + quad * 8;
    unsigned short v[8];
#pragma unroll
    for (int i = 0; i < 8; ++i) v[i] = f2bf(W[(d0 + i) * 256 + f]);
    uint4 o;
    o.x = (unsigned)v[0] | ((unsigned)v[1] << 16);
    o.y = (unsigned)v[2] | ((unsigned)v[3] << 16);
    o.z = (unsigned)v[4] | ((unsigned)v[5] << 16);
    o.w = (unsigned)v[6] | ((unsigned)v[7] << 16);
    *(uint4*)(WTs + (size_t)g * 8) = o;
}

// ---------------- K1: MFMA Wh = h@W; fused s1/s2; WhT [b][f][j] -------------
__global__ __launch_bounds__(256) void k_wh(const float* __restrict__ h,
                                            const unsigned short* __restrict__ WTs,
                                            const float* __restrict__ a,
                                            unsigned short* __restrict__ WhT,
                                            float* __restrict__ s1g,
                                            float* __restrict__ s2g) {
    __shared__ __align__(16) unsigned short A_lds[32][264];   // pad 256->264
    __shared__ __align__(16) unsigned short T_lds[256][44];   // [f][j] pad 32->44
    __shared__ float s1p[32], s2p[32];
    const int t    = threadIdx.x;
    const int lane = t & 63;
    const int wv   = t >> 6;
    const int m    = lane & 15;
    const int quad = lane >> 4;
    const int r0   = blockIdx.x * 32;     // 512 blocks
    const int b    = r0 >> 11;
    const int j0   = r0 & 2047;

    if (t < 32) { s1p[t] = 0.f; s2p[t] = 0.f; }

    // stage h tile fp32 -> bf16 LDS (coalesced float4)
#pragma unroll
    for (int k = 0; k < 8; ++k) {
        const int flat = t + k * 256;
        const int r  = flat >> 6;
        const int d4 = flat & 63;
        float4v hv = *(const float4v*)(h + (size_t)(r0 + r) * 256 + d4 * 4);
        uint2 pk;
        pk.x = (unsigned)f2bf(hv.x) | ((unsigned)f2bf(hv.y) << 16);
        pk.y = (unsigned)f2bf(hv.z) | ((unsigned)f2bf(hv.w) << 16);
        *(uint2*)&A_lds[r][d4 * 4] = pk;
    }
    __syncthreads();

    const int fbase = wv * 64;
    float4v acc[2][4];
#pragma unroll
    for (int it = 0; it < 2; ++it)
#pragma unroll
        for (int ft = 0; ft < 4; ++ft)
#pragma unroll
            for (int r = 0; r < 4; ++r) acc[it][ft][r] = 0.f;

    // swizzled WT: frag(ft,kc) at (wv*4+ft)*4096 + kc*512 + lane*8
    const unsigned short* wtb = WTs + (size_t)(wv * 4) * 4096 + lane * 8;

#pragma unroll
    for (int kc = 0; kc < 8; ++kc) {
        short8 af0 = *(const short8*)&A_lds[m][kc * 32 + quad * 8];
        short8 af1 = *(const short8*)&A_lds[16 + m][kc * 32 + quad * 8];
#pragma unroll
        for (int ft = 0; ft < 4; ++ft) {
            short8 bf = *(const short8*)(wtb + (size_t)ft * 4096 + kc * 512);
            acc[0][ft] = __builtin_amdgcn_mfma_f32_16x16x32_bf16(af0, bf, acc[0][ft], 0, 0, 0);
            acc[1][ft] = __builtin_amdgcn_mfma_f32_16x16x32_bf16(af1, bf, acc[1][ft], 0, 0, 0);
        }
    }

    // fused s1/s2
    float a1v[4], a2v[4];
#pragma unroll
    for (int ft = 0; ft < 4; ++ft) {
        a1v[ft] = a[fbase + ft * 16 + m];
        a2v[ft] = a[256 + fbase + ft * 16 + m];
    }
#pragma unroll
    for (int it = 0; it < 2; ++it) {
#pragma unroll
        for (int reg = 0; reg < 4; ++reg) {
            float v1 = 0.f, v2 = 0.f;
#pragma unroll
            for (int ft = 0; ft < 4; ++ft) {
                const float c = acc[it][ft][reg];
                v1 = fmaf(c, a1v[ft], v1);
                v2 = fmaf(c, a2v[ft], v2);
            }
            v1 += __shfl_xor(v1, 1); v2 += __shfl_xor(v2, 1);
            v1 += __shfl_xor(v1, 2); v2 += __shfl_xor(v2, 2);
            v1 += __shfl_xor(v1, 4); v2 += __shfl_xor(v2, 4);
            v1 += __shfl_xor(v1, 8); v2 += __shfl_xor(v2, 8);
            if (m == 0) {
                const int row = it * 16 + quad * 4 + reg;
                atomicAdd(&s1p[row], v1);
                atomicAdd(&s2p[row], v2);
            }
        }
    }

    // WhT via LDS transpose (same-wave rows -> no barrier needed)
#pragma unroll
    for (int it = 0; it < 2; ++it)
#pragma unroll
        for (int ft = 0; ft < 4; ++ft)
#pragma unroll
            for (int reg = 0; reg < 4; ++reg)
                T_lds[fbase + ft * 16 + m][it * 16 + quad * 4 + reg] =
                    f2bf(acc[it][ft][reg]);

    {
        uint4 o0 = *(const uint4*)&T_lds[t][0];
        uint4 o1 = *(const uint4*)&T_lds[t][8];
        uint4 o2 = *(const uint4*)&T_lds[t][16];
        uint4 o3 = *(const uint4*)&T_lds[t][24];
        unsigned short* wto = WhT + ((size_t)(b * 256 + t) * 2048) + j0;
        *(uint4*)(wto + 0)  = o0;
        *(uint4*)(wto + 8)  = o1;
        *(uint4*)(wto + 16) = o2;
        *(uint4*)(wto + 24) = o3;
    }

    __syncthreads();
    if (t < 32) {
        s1g[(size_t)b * 2048 + j0 + t] = s1p[t];
        s2g[(size_t)b * 2048 + j0 + t] = s2p[t];
    }
}

// ---------------- K3: fused p-compute + MFMA aggregation (m97 structure) ----
// 512 blocks x 256 thr; block = 32 i x 256 f; 32 chunks of 64 j.
static __device__ __forceinline__ uint2 pquad(float4v av, float4v s2v,
                                              float s1, float& rs) {
    float e0 = s1 + s2v.x, e1 = s1 + s2v.y, e2 = s1 + s2v.z, e3 = s1 + s2v.w;
    e0 = fmaxf(e0, ALPHA_ * e0); e1 = fmaxf(e1, ALPHA_ * e1);
    e2 = fmaxf(e2, ALPHA_ * e2); e3 = fmaxf(e3, ALPHA_ * e3);
    const float p0 = (av.x + EPS_) * __expf(e0);
    const float p1 = (av.y + EPS_) * __expf(e1);
    const float p2 = (av.z + EPS_) * __expf(e2);
    const float p3 = (av.w + EPS_) * __expf(e3);
    rs += (p0 + p1) + (p2 + p3);
    uint2 r;
    r.x = (unsigned)f2bf(p0) | ((unsigned)f2bf(p1) << 16);
    r.y = (unsigned)f2bf(p2) | ((unsigned)f2bf(p3) << 16);
    return r;
}

__global__ __launch_bounds__(256, 4) void k_attn(const float* __restrict__ adj,
                                                 const unsigned short* __restrict__ WhT,
                                                 const float* __restrict__ s1g,
                                                 const float* __restrict__ s2g,
                                                 float* __restrict__ out) {
    __shared__ __align__(16) unsigned short A_lds[8 * 32 * 8];    // [q][i] 4KB
    __shared__ __align__(16) unsigned short B_lds[8 * 256 * 8];   // [q][f] 32KB
    __shared__ float rsum_lds[32];

    const int t    = threadIdx.x;
    const int lane = t & 63;
    const int wv   = t >> 6;
    const int m    = lane & 15;
    const int quad = lane >> 4;
    const int b     = blockIdx.x & 7;          // XCD-pinned batch
    const int itile = blockIdx.x >> 3;         // 0..63
    const int i0    = itile * 32;
    const int iloc  = t >> 3;                  // 0..31
    const int c     = t & 7;                   // j-unit within chunk
    const int fbase = wv * 64;

    const float* adjp = adj + (size_t)(b * 2048 + i0 + iloc) * 2048 + c * 8;
    const float* s2p  = s2g + (size_t)b * 2048 + c * 8;
    const float  s1v  = s1g[(size_t)b * 2048 + i0 + iloc];
    const unsigned short* whb = WhT + (size_t)(b * 256) * 2048;

    float4v acc[2][4];   // [it][ft]
#pragma unroll
    for (int it = 0; it < 2; ++it)
#pragma unroll
        for (int ft = 0; ft < 4; ++ft)
#pragma unroll
            for (int r = 0; r < 4; ++r) acc[it][ft][r] = 0.f;

    float rsum = 0.f;

    // prologue: chunk-0 adj/s2 in registers
    float4v adjc0 = *(const float4v*)(adjp);
    float4v adjc1 = *(const float4v*)(adjp + 4);
    float4v s2c0  = *(const float4v*)(s2p);
    float4v s2c1  = *(const float4v*)(s2p + 4);

    for (int ch = 0; ch < 32; ++ch) {
        const int j0 = ch * 64;

        // ---- p (fp32) -> bf16 unit, ds_write into A[q=c][i=iloc] ----
        U8 au;
        uint2 qa = pquad(adjc0, s2c0, s1v, rsum);
        uint2 qb = pquad(adjc1, s2c1, s1v, rsum);
        au.u[0] = qa.x; au.u[1] = qa.y; au.u[2] = qb.x; au.u[3] = qb.y;
        *(uint4*)&A_lds[(c * 32 + iloc) * 8] = au.v4;

        // register-prefetch next chunk's adj/s2
        const int jn = ((ch + 1) & 31) * 64;
        adjc0 = *(const float4v*)(adjp + jn);
        adjc1 = *(const float4v*)(adjp + jn + 4);
        s2c0  = *(const float4v*)(s2p + jn);
        s2c1  = *(const float4v*)(s2p + jn + 4);

        // ---- stage B tile (256f x 64j) from L2-resident WhT via glds ----
#pragma unroll
        for (int k = 0; k < 8; ++k) {
            const int slot = wv * 512 + k * 64 + lane;   // q*256 + f
            const int q = slot >> 8, f = slot & 255;
            GLOAD_LDS16(whb + (size_t)f * 2048 + j0 + q * 8,
                        &B_lds[(wv * 512 + k * 64) * 8]);
        }
        __syncthreads();

        // ---- fragments + 16 MFMAs ----
#pragma unroll
        for (int kc = 0; kc < 2; ++kc) {
            short8 af0 = *(const short8*)&A_lds[((kc * 4 + quad) * 32 + m) * 8];
            short8 af1 = *(const short8*)&A_lds[((kc * 4 + quad) * 32 + 16 + m) * 8];
#pragma unroll
            for (int ft = 0; ft < 4; ++ft) {
                short8 bf = *(const short8*)
                    &B_lds[((kc * 4 + quad) * 256 + fbase + ft * 16 + m) * 8];
                acc[0][ft] = __builtin_amdgcn_mfma_f32_16x16x32_bf16(af0, bf, acc[0][ft], 0, 0, 0);
                acc[1][ft] = __builtin_amdgcn_mfma_f32_16x16x32_bf16(af1, bf, acc[1][ft], 0, 0, 0);
            }
        }
        __syncthreads();
    }

    // rowsum: lanes xor 1,2,4 share iloc (t = iloc*8 + c)
    rsum += __shfl_xor(rsum, 1);
    rsum += __shfl_xor(rsum, 2);
    rsum += __shfl_xor(rsum, 4);
    if (c == 0) rsum_lds[iloc] = rsum;
    __syncthreads();

    // epilogue: C/D col = lane&15 (f), row = quad*4+reg (i), +16 per it
#pragma unroll
    for (int it = 0; it < 2; ++it) {
#pragma unroll
        for (int reg = 0; reg < 4; ++reg) {
            const int row = it * 16 + quad * 4 + reg;
            const float inv = 1.0f / rsum_lds[row];
#pragma unroll
            for (int ft = 0; ft < 4; ++ft) {
                out[(size_t)(b * 2048 + i0 + row) * 256 + fbase + ft * 16 + m] =
                    acc[it][ft][reg] * inv;
            }
        }
    }
}

extern "C" void kernel_launch(void* const* d_in, const int* in_sizes, int n_in,
                              void* d_out, int out_size, void* d_ws, size_t ws_size,
                              hipStream_t stream) {
    const float* h   = (const float*)d_in[0];   // (8,2048,256)
    const float* adj = (const float*)d_in[1];   // (8,2048,2048)
    const float* W   = (const float*)d_in[2];   // (256,256)
    const float* a   = (const float*)d_in[3];   // (512,1)
    float* out = (float*)d_out;                 // (8,2048,256)

    unsigned short* WhT = (unsigned short*)d_ws;                        // 8.4 MB
    unsigned short* WTs = (unsigned short*)((char*)d_ws + 8388608);     // 128 KB
    float*          s1  = (float*)((char*)d_ws + 8388608 + 131072);     // 64 KB
    float*          s2  = s1 + 16384;                                   // 64 KB

    k_wt  <<<dim3(32),  dim3(256), 0, stream>>>(W, WTs);
    k_wh  <<<dim3(512), dim3(256), 0, stream>>>(h, WTs, a, WhT, s1, s2);
    k_attn<<<dim3(512), dim3(256), 0, stream>>>(adj, WhT, s1, s2, out);
}